// Round 6
// baseline (212.465 us; speedup 1.0000x reference)
//
#include <hip/hip_runtime.h>

// Combine: out[b,:] = branches[argmax(gate[b,:4])][b,:]
// B=4096 rows, D=4096 fp32/row, N=4 branches. Memory-bound select-copy.
//
// v6: nt x MLP. v5 (nt-load+nt-store, flat) was the first lever to move dur
// (40.6-41.8 -> <39.4us, fell out of rocprof top-5). But v5's loop collapsed
// to VGPR=8 => 1 outstanding nt-load per thread per iteration. v6 hoists all
// 8 gate selects (cached: gate is hot in L2), then issues all 8 nt data
// loads into distinct named registers, then all 8 nt stores. Tests whether
// batched nt misses pipeline better, and recaptures combine's FETCH_SIZE to
// resolve whether nt-load raised HBM reads (=> HBM headroom proven).

#define B 4096
#define D 4096
#define NV4 (B * D / 4)            // 4,194,304 float4s
#define THREADS 256
#define BLOCKS 2048                // 8 blocks/CU -> 32 waves/CU
#define STRIDE (THREADS * BLOCKS)  // 524,288 threads
#define ITERS 8                    // NV4 / STRIDE, exact (no tail)

typedef float f32x4 __attribute__((ext_vector_type(4)));

__device__ __forceinline__ const f32x4* pick_src(
    const f32x4* g4, const f32x4* s0, const f32x4* s1,
    const f32x4* s2, const f32x4* s3, size_t idx) {
    const int row = (int)(idx >> 10);  // D/4 = 1024 float4 per row
    // First-occurrence argmax (strict >) matches jnp.argmax tie-break.
    f32x4 g = g4[row];
    int sel = 0;
    float best = g.x;
    if (g.y > best) { best = g.y; sel = 1; }
    if (g.z > best) { best = g.z; sel = 2; }
    if (g.w > best) { best = g.w; sel = 3; }
    return (sel == 0) ? s0 : (sel == 1) ? s1 : (sel == 2) ? s2 : s3;
}

__global__ __launch_bounds__(THREADS) void combine_kernel(
    const float* __restrict__ b0, const float* __restrict__ b1,
    const float* __restrict__ b2, const float* __restrict__ b3,
    const float* __restrict__ gate, float* __restrict__ out) {

    const f32x4* __restrict__ g4 = (const f32x4*)gate;
    const f32x4* __restrict__ s0 = (const f32x4*)b0;
    const f32x4* __restrict__ s1 = (const f32x4*)b1;
    const f32x4* __restrict__ s2 = (const f32x4*)b2;
    const f32x4* __restrict__ s3 = (const f32x4*)b3;
    f32x4* __restrict__ d4 = (f32x4*)out;

    const size_t i0 = (size_t)blockIdx.x * THREADS + threadIdx.x;
    const size_t i1 = i0 + 1 * (size_t)STRIDE;
    const size_t i2 = i0 + 2 * (size_t)STRIDE;
    const size_t i3 = i0 + 3 * (size_t)STRIDE;
    const size_t i4 = i0 + 4 * (size_t)STRIDE;
    const size_t i5 = i0 + 5 * (size_t)STRIDE;
    const size_t i6 = i0 + 6 * (size_t)STRIDE;
    const size_t i7 = i0 + 7 * (size_t)STRIDE;

    // Phase 1: all gate selects (cached loads; gate is 64KB, L2-hot).
    const f32x4* p0 = pick_src(g4, s0, s1, s2, s3, i0);
    const f32x4* p1 = pick_src(g4, s0, s1, s2, s3, i1);
    const f32x4* p2 = pick_src(g4, s0, s1, s2, s3, i2);
    const f32x4* p3 = pick_src(g4, s0, s1, s2, s3, i3);
    const f32x4* p4 = pick_src(g4, s0, s1, s2, s3, i4);
    const f32x4* p5 = pick_src(g4, s0, s1, s2, s3, i5);
    const f32x4* p6 = pick_src(g4, s0, s1, s2, s3, i6);
    const f32x4* p7 = pick_src(g4, s0, s1, s2, s3, i7);

    // Phase 2: all 8 nt loads in flight (distinct regs, no WAR hazards).
    f32x4 v0 = __builtin_nontemporal_load(&p0[i0]);
    f32x4 v1 = __builtin_nontemporal_load(&p1[i1]);
    f32x4 v2 = __builtin_nontemporal_load(&p2[i2]);
    f32x4 v3 = __builtin_nontemporal_load(&p3[i3]);
    f32x4 v4 = __builtin_nontemporal_load(&p4[i4]);
    f32x4 v5 = __builtin_nontemporal_load(&p5[i5]);
    f32x4 v6 = __builtin_nontemporal_load(&p6[i6]);
    f32x4 v7 = __builtin_nontemporal_load(&p7[i7]);

    // Phase 3: all 8 nt stores (write-once data; no cache allocation).
    __builtin_nontemporal_store(v0, &d4[i0]);
    __builtin_nontemporal_store(v1, &d4[i1]);
    __builtin_nontemporal_store(v2, &d4[i2]);
    __builtin_nontemporal_store(v3, &d4[i3]);
    __builtin_nontemporal_store(v4, &d4[i4]);
    __builtin_nontemporal_store(v5, &d4[i5]);
    __builtin_nontemporal_store(v6, &d4[i6]);
    __builtin_nontemporal_store(v7, &d4[i7]);
}

extern "C" void kernel_launch(void* const* d_in, const int* in_sizes, int n_in,
                              void* d_out, int out_size, void* d_ws, size_t ws_size,
                              hipStream_t stream) {
    const float* b0   = (const float*)d_in[0];
    const float* b1   = (const float*)d_in[1];
    const float* b2   = (const float*)d_in[2];
    const float* b3   = (const float*)d_in[3];
    const float* gate = (const float*)d_in[4];
    float* out = (float*)d_out;

    combine_kernel<<<BLOCKS, THREADS, 0, stream>>>(b0, b1, b2, b3, gate, out);
}

// Round 7
// 211.260 us; speedup vs baseline: 1.0057x; 1.0057x over previous
//
#include <hip/hip_runtime.h>

// Combine: out[b,:] = branches[argmax(gate[b,:4])][b,:]
// B=4096 rows, D=4096 fp32/row, N=4 branches. Memory-bound select-copy.
//
// v7: v6 with the schedule PINNED. v6 (source-level 3-phase batch) slightly
// regressed vs v5's simple loop — but combine fell out of rocprof top-5 both
// rounds, so v6's VGPR was never observed and the compiler may have sunk
// each store next to its load (it collapsed v1's unroll to VGPR=8 the same
// way), never actually testing 8-deep MLP in the flat+nt regime.
// v7 forces it: 8 gate selects -> 8 nt loads -> sched_barrier(0) (hard
// compile-time fence, nothing crosses) -> 8 nt stores.
// Decisive: VGPR>=64 proves the batch exists. dur ~25-30us => MLP was the
// wall. dur still ~40us => MLP hardware-proven dead; declare measured
// ceiling next round (dependent gather-copy ~3.4 TB/s total-moved vs
// 6.5 TB/s for the dependency-free fill in the same session).

#define B 4096
#define D 4096
#define THREADS 256
#define BLOCKS 2048                // 8 blocks/CU resident across 256 CUs
#define STRIDE (THREADS * BLOCKS)  // 524,288 threads; NV4/STRIDE = 8 exact

typedef float f32x4 __attribute__((ext_vector_type(4)));

__device__ __forceinline__ const f32x4* pick_src(
    const f32x4* g4, const f32x4* s0, const f32x4* s1,
    const f32x4* s2, const f32x4* s3, size_t idx) {
    const int row = (int)(idx >> 10);  // D/4 = 1024 float4 per row
    // First-occurrence argmax (strict >) matches jnp.argmax tie-break.
    f32x4 g = g4[row];
    int sel = 0;
    float best = g.x;
    if (g.y > best) { best = g.y; sel = 1; }
    if (g.z > best) { best = g.z; sel = 2; }
    if (g.w > best) { best = g.w; sel = 3; }
    return (sel == 0) ? s0 : (sel == 1) ? s1 : (sel == 2) ? s2 : s3;
}

__global__ __launch_bounds__(THREADS) void combine_kernel(
    const float* __restrict__ b0, const float* __restrict__ b1,
    const float* __restrict__ b2, const float* __restrict__ b3,
    const float* __restrict__ gate, float* __restrict__ out) {

    const f32x4* __restrict__ g4 = (const f32x4*)gate;
    const f32x4* __restrict__ s0 = (const f32x4*)b0;
    const f32x4* __restrict__ s1 = (const f32x4*)b1;
    const f32x4* __restrict__ s2 = (const f32x4*)b2;
    const f32x4* __restrict__ s3 = (const f32x4*)b3;
    f32x4* __restrict__ d4 = (f32x4*)out;

    const size_t i0 = (size_t)blockIdx.x * THREADS + threadIdx.x;
    const size_t i1 = i0 + 1 * (size_t)STRIDE;
    const size_t i2 = i0 + 2 * (size_t)STRIDE;
    const size_t i3 = i0 + 3 * (size_t)STRIDE;
    const size_t i4 = i0 + 4 * (size_t)STRIDE;
    const size_t i5 = i0 + 5 * (size_t)STRIDE;
    const size_t i6 = i0 + 6 * (size_t)STRIDE;
    const size_t i7 = i0 + 7 * (size_t)STRIDE;

    // Phase 1: gate selects (cached; gate is 64KB and cache-hot).
    const f32x4* p0 = pick_src(g4, s0, s1, s2, s3, i0);
    const f32x4* p1 = pick_src(g4, s0, s1, s2, s3, i1);
    const f32x4* p2 = pick_src(g4, s0, s1, s2, s3, i2);
    const f32x4* p3 = pick_src(g4, s0, s1, s2, s3, i3);
    const f32x4* p4 = pick_src(g4, s0, s1, s2, s3, i4);
    const f32x4* p5 = pick_src(g4, s0, s1, s2, s3, i5);
    const f32x4* p6 = pick_src(g4, s0, s1, s2, s3, i6);
    const f32x4* p7 = pick_src(g4, s0, s1, s2, s3, i7);

    // Phase 2: 8 nt loads, guaranteed all issued before any store.
    f32x4 v0 = __builtin_nontemporal_load(&p0[i0]);
    f32x4 v1 = __builtin_nontemporal_load(&p1[i1]);
    f32x4 v2 = __builtin_nontemporal_load(&p2[i2]);
    f32x4 v3 = __builtin_nontemporal_load(&p3[i3]);
    f32x4 v4 = __builtin_nontemporal_load(&p4[i4]);
    f32x4 v5 = __builtin_nontemporal_load(&p5[i5]);
    f32x4 v6 = __builtin_nontemporal_load(&p6[i6]);
    f32x4 v7 = __builtin_nontemporal_load(&p7[i7]);

    // Hard scheduling fence: no instruction (IR or MIR) crosses.
    __builtin_amdgcn_sched_barrier(0);

    // Phase 3: 8 nt stores.
    __builtin_nontemporal_store(v0, &d4[i0]);
    __builtin_nontemporal_store(v1, &d4[i1]);
    __builtin_nontemporal_store(v2, &d4[i2]);
    __builtin_nontemporal_store(v3, &d4[i3]);
    __builtin_nontemporal_store(v4, &d4[i4]);
    __builtin_nontemporal_store(v5, &d4[i5]);
    __builtin_nontemporal_store(v6, &d4[i6]);
    __builtin_nontemporal_store(v7, &d4[i7]);
}

extern "C" void kernel_launch(void* const* d_in, const int* in_sizes, int n_in,
                              void* d_out, int out_size, void* d_ws, size_t ws_size,
                              hipStream_t stream) {
    const float* b0   = (const float*)d_in[0];
    const float* b1   = (const float*)d_in[1];
    const float* b2   = (const float*)d_in[2];
    const float* b3   = (const float*)d_in[3];
    const float* gate = (const float*)d_in[4];
    float* out = (float*)d_out;

    combine_kernel<<<BLOCKS, THREADS, 0, stream>>>(b0, b1, b2, b3, gate, out);
}